// Round 6
// baseline (299.816 us; speedup 1.0000x reference)
//
#include <hip/hip_runtime.h>

// AttentionWindow (BEiT windowed attention), MI355X gfx950.
// B=64 N=197 DIM=768 H=12 hd=64. bf16 MFMA (16x16x32), fp32 softmax.
// R13: k_prep ELIMINATED (3 -> 2 launches). Non-k_fused pool has been fixed
//      at ~127us across 4 reworks of k_prep/k_proj => fixed per-launch
//      overhead dominates it; fewer kernels is the only lever.
//      - k_fused stages fp32 x / qkv-weights via T14 reg-staging (issue-early
//        float4 loads, in-reg f2bf convert, write-late ds_write_b128) into
//        the SAME swizzled LDS image the DMA produced. 2 buffers, 1 raw
//        barrier/phase, mid-phase vmcnt(0) drains exactly this phase's loads.
//      - rel-pos bias gathered in-softmax (rpb[relidx[qk]*12+h], L1-resident).
//      - k_proj: A (att_ws bf16) + B (projw fp32, in-reg convert) both
//        reg-staged, same protocol; LDS 32KB.
//      Compute/epilogue/attention math identical to R11/R12 (absmax-verified).

#define B_    64
#define N_    197
#define DIM_  768
#define H_    12
#define HD_   64
#define M_TOT (B_ * N_)     // 12608

// fused LDS map (shorts): 2 staging buffers (A 13312 + B 12288 each) = 51200
// shorts = 102.4 KB. Q/K/VT (end 40960) overlays them after the loop.
#define ST_A0   0
#define ST_B0   13312
#define ST_A1   25600
#define ST_B1   38912        // end 51200
#define OFF_Q   0            // 208 rows x 64, XOR-swizzled slots
#define OFF_K   13312        // 208 rows x 64
#define OFF_VT  26624        // 64 rows (d) x 224 (tok), group-swizzled
#define LDS_TOT 51200

typedef __attribute__((ext_vector_type(8))) short bf8;
typedef __attribute__((ext_vector_type(4))) float f4;
typedef __attribute__((ext_vector_type(4))) unsigned short us4;

__device__ __forceinline__ unsigned short f2bf(float f) {
    unsigned u = __float_as_uint(f);
    u = (u + 0x7fffu + ((u >> 16) & 1u)) >> 16;
    return (unsigned short)u;
}

// Q/K LDS address (shorts): row-stride 64, 16B slot XOR-swizzled by row.
__device__ __forceinline__ int qkaddr(int row, int col) {
    return row * 64 + ((((col >> 3) ^ row) & 7) << 3) + (col & 7);
}
// VT LDS address (shorts): d-stride 224; 28 slots/row; XOR within slot groups
// (full 8-groups for s<24, the tail group of 4 uses a 2-bit XOR).
__device__ __forceinline__ int vtaddr(int d, int k) {
    int s = k >> 3;
    int s2 = (s < 24) ? ((s & 24) | ((s ^ d) & 7)) : (24 + ((s ^ d) & 3));
    return d * 224 + (s2 << 3) + (k & 7);
}

// pack 8 fp32 -> 16B of bf16
union pk16 { us4 u[2]; uint4 q; };
__device__ __forceinline__ uint4 cvt8(const float4& lo, const float4& hi) {
    pk16 p;
    p.u[0] = (us4){f2bf(lo.x), f2bf(lo.y), f2bf(lo.z), f2bf(lo.w)};
    p.u[1] = (us4){f2bf(hi.x), f2bf(hi.y), f2bf(hi.z), f2bf(hi.w)};
    return p.q;
}

// ---------------- fused QKV + attention, one block (1024 thr) per (b,h) ----------------
__global__ __launch_bounds__(1024) void k_fused(const float* __restrict__ X32,
                                                const float* __restrict__ W32,
                                                const float* __restrict__ qb,
                                                const float* __restrict__ vbias,
                                                const float* __restrict__ rpb,
                                                const int* __restrict__ relidx,
                                                unsigned short* __restrict__ att_ws) {
    __shared__ unsigned short lds[LDS_TOT];

    const int t = threadIdx.x;                 // 0..1023
    const int w = t >> 6, lane = t & 63, ln = lane & 15, quad = lane >> 4;
    const int wm = w >> 2, wn = w & 3;         // SIMD-balanced: SIMD w%4 hosts wm 0..3
    const int srl = lane >> 3;                 // local row 0..7 within 8-row group
    const int src8 = (lane & 7) ^ srl;         // stored-slot -> fetched-chunk XOR swizzle

    // XCD swizzle: gid%8 -> XCD; contiguous 8-b group per XCD keeps x in its L2
    const int gid = blockIdx.x;                // 0..767
    const int local = gid >> 3;                // 0..95
    const int b = (gid & 7) * 8 + (local & 7);
    const int h = local >> 3;                  // 0..11

    const float* xb = X32 + (size_t)b * 197 * 768;

    // ---- T14 reg-staging (BK=64): 50 slots/phase (26 A + 24 B) over 16 waves,
    // reversed so the 4-slot waves (14,15) carry the lightest MFMA load (wm=3).
    // Each slot: 2x float4 load -> cvt8 -> one 16B LDS write at base+lane*16B
    // (identical image to the old global_load_lds staging).
    float4 rg[8];                              // single set: live within one phase

    auto ldreg = [&](int kt) {
#pragma unroll
        for (int i = 0; i < 4; ++i) {
            int idx = (15 - w) + 16 * i;
            if (idx >= 50) break;              // wave-uniform
            const float* src;
            if (idx < 26) {                    // A: token rows idx*8..+7
                int tok = 8 * idx + srl;
                if (tok > 196) tok = 196;      // clamp; pad rows discarded later
                src = xb + (size_t)tok * 768 + kt * 64 + src8 * 8;
            } else {                           // B: weight rows (3 passes x 64)
                int bb = idx - 26;
                int rr = 8 * bb + srl;         // 0..191
                src = W32 + (size_t)((rr >> 6) * 768 + h * 64 + (rr & 63)) * 768
                          + kt * 64 + src8 * 8;
            }
            rg[2 * i]     = *(const float4*)(src);
            rg[2 * i + 1] = *(const float4*)(src + 4);
        }
    };
    auto wrreg = [&](int aOfs, int bOfs) {
#pragma unroll
        for (int i = 0; i < 4; ++i) {
            int idx = (15 - w) + 16 * i;
            if (idx >= 50) break;              // wave-uniform
            uint4 v = cvt8(rg[2 * i], rg[2 * i + 1]);
            unsigned short* dst = (idx < 26)
                ? &lds[aOfs + idx * 512 + lane * 8]
                : &lds[bOfs + (idx - 26) * 512 + lane * 8];
            *(uint4*)dst = v;
        }
    };

    f4 acc[4][3] = {};                         // [mi][tl]: wave tile = (4m x 4n), 12 tiles

    auto compute = [&](int aOfs, int bOfs) {
#pragma unroll
        for (int ks = 0; ks < 2; ++ks) {
            bf8 bfr[3];
#pragma unroll
            for (int tl = 0; tl < 3; ++tl) {
                int rr = (wn * 3 + tl) * 16 + ln;
                int slot = (ks * 4 + quad) ^ (rr & 7);
                bfr[tl] = *(const bf8*)&lds[bOfs + rr * 64 + slot * 8];
            }
            __builtin_amdgcn_s_setprio(1);
#pragma unroll
            for (int mi = 0; mi < 4; ++mi) {
                int mt = wm + 4 * mi;
                if (mt >= 13) continue;        // wave-uniform (only wm>0, mi=3)
                int row = mt * 16 + ln;
                int slot = (ks * 4 + quad) ^ (row & 7);
                bf8 af = *(const bf8*)&lds[aOfs + row * 64 + slot * 8];
#pragma unroll
                for (int tl = 0; tl < 3; ++tl)
                    acc[mi][tl] = __builtin_amdgcn_mfma_f32_16x16x32_bf16(
                        af, bfr[tl], acc[mi][tl], 0, 0, 0);
            }
            __builtin_amdgcn_s_setprio(0);
        }
    };

    // ---- pipelined K-loop: [ldreg(kt+1)] [compute(kt)] [vmcnt(0); write kt+1
    //      to other buffer] [lgkm; barrier]. Loads in flight across compute;
    //      ONE barrier/phase; writes target the buffer whose readers passed
    //      the previous barrier.
    ldreg(0);
    __asm__ __volatile__("s_waitcnt vmcnt(0)" ::: "memory");
    wrreg(ST_A0, ST_B0);
    __syncthreads();
#pragma unroll
    for (int kt = 0; kt < 12; ++kt) {
        if (kt + 1 < 12) ldreg(kt + 1);
        compute((kt & 1) ? ST_A1 : ST_A0, (kt & 1) ? ST_B1 : ST_B0);
        if (kt + 1 < 12) {
            __asm__ __volatile__("s_waitcnt vmcnt(0)" ::: "memory");
            wrreg((kt & 1) ? ST_A0 : ST_A1, (kt & 1) ? ST_B0 : ST_B1);
        }
        __builtin_amdgcn_sched_barrier(0);
        __asm__ __volatile__("s_waitcnt lgkmcnt(0)" ::: "memory");
        __builtin_amdgcn_sched_barrier(0);
        __builtin_amdgcn_s_barrier();
    }
    __syncthreads();                           // staging dead: epilogue overlays it

    // ---- epilogue: C/D layout row=quad*4+r, col=ln (m89-verified) -> LDS Q/K/VT
#pragma unroll
    for (int tl = 0; tl < 3; ++tl) {
        int tn = wn * 3 + tl;
        int p = tn >> 2;                       // 0=Q 1=K 2=V
        int col = (tn & 3) * 16 + ln;          // 0..63 within the pass
        int d = h * 64 + col;
        float bj = (p == 0) ? qb[d] : (p == 2) ? vbias[d] : 0.0f;
#pragma unroll
        for (int mi = 0; mi < 4; ++mi) {
            int mt = wm + 4 * mi;
            if (mt >= 13) continue;
#pragma unroll
            for (int r = 0; r < 4; ++r) {
                int row = mt * 16 + quad * 4 + r;  // 0..207 (pad rows masked later)
                float v = acc[mi][tl][r];
                if (p == 0)      lds[OFF_Q + qkaddr(row, col)] = f2bf((v + bj) * 0.125f);
                else if (p == 1) lds[OFF_K + qkaddr(row, col)] = f2bf(v);
                else             lds[OFF_VT + vtaddr(col, row)] = f2bf(v + bj);
            }
        }
    }
    // zero VT K-pad cols 208..223 (cols 197..207 hold finite clamped data)
    for (int idx = t; idx < 64 * 16; idx += 1024) {
        int d = idx >> 4, k = 208 + (idx & 15);
        lds[OFF_VT + vtaddr(d, k)] = 0;
    }
    __syncthreads();

    // ---- attention (Q/K/VT in LDS, P fully in-register), 16 waves, 13 m-tiles ----
    for (int mt = w; mt < 13; mt += 16) {
        // Q as B-operand (hoisted): lane ln supplies q-row mt*16+ln
        bf8 qa[2];
#pragma unroll
        for (int ks = 0; ks < 2; ++ks)
            qa[ks] = *(const bf8*)&lds[OFF_Q + qkaddr(mt * 16 + ln, ks * 32 + quad * 8)];

        // swapped QK: S^T[k][q];  lane(ln,quad) reg r holds S[q=mt*16+ln][k=nt*16+quad*4+r]
        f4 sacc[13];
#pragma unroll
        for (int nt = 0; nt < 13; ++nt) sacc[nt] = (f4){0.f, 0.f, 0.f, 0.f};
        __builtin_amdgcn_s_setprio(1);
#pragma unroll
        for (int nt = 0; nt < 13; ++nt) {
#pragma unroll
            for (int ks = 0; ks < 2; ++ks) {
                bf8 ka = *(const bf8*)&lds[OFF_K + qkaddr(nt * 16 + ln, ks * 32 + quad * 8)];
                sacc[nt] = __builtin_amdgcn_mfma_f32_16x16x32_bf16(ka, qa[ks], sacc[nt], 0, 0, 0);
            }
        }
        __builtin_amdgcn_s_setprio(0);

        // softmax: row is lane-local across (nt,r); cross-lane only over quad (2 shfl)
        // rel-pos bias gathered directly: rpb[relidx[q*197+k]*12+h] (L1-resident)
        int qg = mt * 16 + ln;
        const int* relrow = relidx + (size_t)(qg < 197 ? qg : 196) * 197;
        float mx = -3.0e38f;
#pragma unroll
        for (int nt = 0; nt < 13; ++nt)
#pragma unroll
            for (int r = 0; r < 4; ++r) {
                int kg = nt * 16 + quad * 4 + r;
                float s = (kg < 197) ? (sacc[nt][r] + rpb[relrow[kg] * H_ + h])
                                     : -3.0e38f;
                sacc[nt][r] = s;
                mx = fmaxf(mx, s);
            }
        mx = fmaxf(mx, __shfl_xor(mx, 16, 64));
        mx = fmaxf(mx, __shfl_xor(mx, 32, 64));
        float sum = 0.f;
#pragma unroll
        for (int nt = 0; nt < 13; ++nt)
#pragma unroll
            for (int r = 0; r < 4; ++r) {
                float pv = __expf(sacc[nt][r] - mx);
                sacc[nt][r] = pv;
                sum += pv;
            }
        sum += __shfl_xor(sum, 16, 64);
        sum += __shfl_xor(sum, 32, 64);
        float inv = 1.0f / sum;

        // pack normalized P to bf16 pairs: pk[nt][0]=(r0,r1), pk[nt][1]=(r2,r3)
        unsigned pk[14][2];
#pragma unroll
        for (int nt = 0; nt < 13; ++nt) {
            pk[nt][0] = (unsigned)f2bf(sacc[nt][0] * inv) |
                        ((unsigned)f2bf(sacc[nt][1] * inv) << 16);
            pk[nt][1] = (unsigned)f2bf(sacc[nt][2] * inv) |
                        ((unsigned)f2bf(sacc[nt][3] * inv) << 16);
        }
        pk[13][0] = 0; pk[13][1] = 0;          // K-pad 208..223 -> P = 0

        // PV: A-frag (lane ln = q-row ln, k-chunk = quad*8) built by ds_bpermute:
        // target quad q_t takes k=32ks+8q_t+[0..7] from source lanes
        // (ln + 32*(q_t&1)) and (+16), register set nt = 2ks + (q_t>>1).
        const int sA = (((lane & 15) | ((lane & 16) << 1)) << 2);
        const int sB = sA + 64;
        const bool hi = (lane & 32) != 0;
        f4 o[4];
#pragma unroll
        for (int j = 0; j < 4; ++j) o[j] = (f4){0.f, 0.f, 0.f, 0.f};
#pragma unroll
        for (int ks = 0; ks < 7; ++ks) {
            int b0 = __builtin_amdgcn_ds_bpermute(sA, (int)pk[2 * ks][0]);
            int b1 = __builtin_amdgcn_ds_bpermute(sA, (int)pk[2 * ks][1]);
            int b2 = __builtin_amdgcn_ds_bpermute(sB, (int)pk[2 * ks][0]);
            int b3 = __builtin_amdgcn_ds_bpermute(sB, (int)pk[2 * ks][1]);
            int c0 = __builtin_amdgcn_ds_bpermute(sA, (int)pk[2 * ks + 1][0]);
            int c1 = __builtin_amdgcn_ds_bpermute(sA, (int)pk[2 * ks + 1][1]);
            int c2 = __builtin_amdgcn_ds_bpermute(sB, (int)pk[2 * ks + 1][0]);
            int c3 = __builtin_amdgcn_ds_bpermute(sB, (int)pk[2 * ks + 1][1]);
            union { int u[4]; bf8 v; } uu;
            uu.u[0] = hi ? c0 : b0;
            uu.u[1] = hi ? c1 : b1;
            uu.u[2] = hi ? c2 : b2;
            uu.u[3] = hi ? c3 : b3;
            __builtin_amdgcn_s_setprio(1);
#pragma unroll
            for (int j = 0; j < 4; ++j) {
                bf8 vf = *(const bf8*)&lds[OFF_VT + vtaddr(j * 16 + ln, ks * 32 + quad * 8)];
                o[j] = __builtin_amdgcn_mfma_f32_16x16x32_bf16(uu.v, vf, o[j], 0, 0, 0);
            }
            __builtin_amdgcn_s_setprio(0);
        }
#pragma unroll
        for (int j = 0; j < 4; ++j)
#pragma unroll
            for (int r = 0; r < 4; ++r) {
                int tok = mt * 16 + quad * 4 + r;
                if (tok < 197)
                    att_ws[((size_t)b * 197 + tok) * 768 + h * 64 + j * 16 + ln] = f2bf(o[j][r]);
            }
    }
}

// ---------------- proj GEMM: (12608x768) @ (768x768)^T + bias -> fp32 out ----------------
// R13: A (att_ws bf16) + B (projw fp32 -> in-reg convert) both reg-staged,
// T14 protocol, 2 x 16KB buffers (32KB LDS).
#define PJ_BUF 8192

__global__ __launch_bounds__(256, 3) void k_proj(const unsigned short* __restrict__ A,
                                                 const float* __restrict__ Bw32,
                                                 const float* __restrict__ pb,
                                                 float* __restrict__ out) {
    __shared__ unsigned short plds[2 * PJ_BUF];
    const int t = threadIdx.x;
    const int w = t >> 6, lane = t & 63, ln = lane & 15, quad = lane >> 4;
    const int wm = w & 1, wn = w >> 1;

    const int gid = blockIdx.x;                 // panels: 8 bm x 6 bn = 48
    const int panel = gid / 48, rem = gid - panel * 48;
    const int pm0 = panel * 8;
    const int psz = (99 - pm0 < 8) ? (99 - pm0) : 8;
    const int bm = pm0 + rem % psz;
    const int bn = rem / psz;

    const int srl = lane >> 3;
    const int src8 = (lane & 7) ^ srl;

    uint4  ra[2];                              // A chunks (bf16, 16B)
    float4 rb[4];                              // B chunks (fp32, 2 x 16B each)

    auto pld = [&](int kt) {
#pragma unroll
        for (int i = 0; i < 2; ++i) {
            int idx = w * 2 + i;               // 0..7 superrow groups
            int gr = bm * 128 + 2 * (idx * 8 + srl) + (src8 >> 2);
            if (gr > M_TOT - 1) gr = M_TOT - 1;
            ra[i] = *(const uint4*)(A + (size_t)gr * 768 + kt * 32 + (src8 & 3) * 8);
            int gc = bn * 128 + 2 * (idx * 8 + srl) + (src8 >> 2);   // < 768
            const float* s = Bw32 + (size_t)gc * 768 + kt * 32 + (src8 & 3) * 8;
            rb[2 * i]     = *(const float4*)(s);
            rb[2 * i + 1] = *(const float4*)(s + 4);
        }
    };
    auto pwr = [&](unsigned short* buf) {
#pragma unroll
        for (int i = 0; i < 2; ++i) {
            int idx = w * 2 + i;
            *(uint4*)&buf[idx * 512 + lane * 8] = ra[i];
            *(uint4*)&buf[4096 + idx * 512 + lane * 8] = cvt8(rb[2 * i], rb[2 * i + 1]);
        }
    };
    auto pcomp = [&](const unsigned short* buf, f4 (*acc)[4]) {
        bf8 af[4], bfr[4];
#pragma unroll
        for (int i = 0; i < 4; ++i) {
            int row = wm * 64 + i * 16 + ln;
            int sr = row >> 1;
            int slot = (((row & 1) << 2) | quad) ^ (sr & 7);
            af[i] = *(const bf8*)&buf[sr * 64 + slot * 8];
        }
#pragma unroll
        for (int j = 0; j < 4; ++j) {
            int row = wn * 64 + j * 16 + ln;
            int sr = row >> 1;
            int slot = (((row & 1) << 2) | quad) ^ (sr & 7);
            bfr[j] = *(const bf8*)&buf[4096 + sr * 64 + slot * 8];
        }
        __builtin_amdgcn_s_setprio(1);
#pragma unroll
        for (int i = 0; i < 4; ++i)
#pragma unroll
            for (int j = 0; j < 4; ++j)
                acc[i][j] = __builtin_amdgcn_mfma_f32_16x16x32_bf16(af[i], bfr[j], acc[i][j], 0, 0, 0);
        __builtin_amdgcn_s_setprio(0);
    };

    f4 acc[4][4] = {};

    pld(0);
    __asm__ __volatile__("s_waitcnt vmcnt(0)" ::: "memory");
    pwr(&plds[0]);
    __syncthreads();
#pragma unroll
    for (int kt = 0; kt < 24; ++kt) {
        if (kt + 1 < 24) pld(kt + 1);
        pcomp(&plds[(kt & 1) * PJ_BUF], acc);
        if (kt + 1 < 24) {
            __asm__ __volatile__("s_waitcnt vmcnt(0)" ::: "memory");
            pwr(&plds[((kt + 1) & 1) * PJ_BUF]);
        }
        __builtin_amdgcn_sched_barrier(0);
        __asm__ __volatile__("s_waitcnt lgkmcnt(0)" ::: "memory");
        __builtin_amdgcn_sched_barrier(0);
        __builtin_amdgcn_s_barrier();
    }

#pragma unroll
    for (int i = 0; i < 4; ++i) {
#pragma unroll
        for (int r = 0; r < 4; ++r) {
            int row_g = bm * 128 + wm * 64 + i * 16 + quad * 4 + r;
            if (row_g >= M_TOT) continue;
#pragma unroll
            for (int j = 0; j < 4; ++j) {
                int col_g = bn * 128 + wn * 64 + j * 16 + ln;
                out[(size_t)row_g * 768 + col_g] = acc[i][j][r] + pb[col_g];
            }
        }
    }
}

extern "C" void kernel_launch(void* const* d_in, const int* in_sizes, int n_in,
                              void* d_out, int out_size, void* d_ws, size_t ws_size,
                              hipStream_t stream) {
    const float* x     = (const float*)d_in[0];
    const float* qkvw  = (const float*)d_in[1];
    const float* qb    = (const float*)d_in[2];
    const float* vb    = (const float*)d_in[3];
    const float* rpb   = (const float*)d_in[4];
    const float* projw = (const float*)d_in[5];
    const float* pb    = (const float*)d_in[6];
    const int*   ridx  = (const int*)d_in[7];
    float* out = (float*)d_out;

    char* ws = (char*)d_ws;
    size_t off = 0;
    auto alloc = [&](size_t bytes) -> void* {
        void* p = ws + off;
        off = (off + bytes + 255) & ~(size_t)255;
        return p;
    };
    unsigned short* att_ws = (unsigned short*)alloc((size_t)(M_TOT + 64) * DIM_ * 2);
    (void)ws_size; (void)in_sizes; (void)n_in; (void)out_size;

    k_fused<<<768, 1024, 0, stream>>>(x, qkvw, qb, vb, rpb, ridx, att_ws);
    k_proj<<<594, 256, 0, stream>>>(att_ws, projw, pb, out);
}

// Round 7
// 204.924 us; speedup vs baseline: 1.4631x; 1.4631x over previous
//
#include <hip/hip_runtime.h>

// AttentionWindow (BEiT windowed attention), MI355X gfx950.
// B=64 N=197 DIM=768 H=12 hd=64. bf16 MFMA (16x16x32), fp32 softmax.
// R14: REVERT to R12 (best verified, 211.0us). R13's fp32 reg-staging
//      doubled k_fused FETCH (48->102MB) and halved MfmaUtil (27->14):
//      per-head redundant fp32 reads + ds_write/ds_read LDS contention +
//      per-phase vmcnt(0)+lgkmcnt(0) serial drains. DMA staging + k_prep
//      conversion restored.

#define B_    64
#define N_    197
#define DIM_  768
#define H_    12
#define HD_   64
#define M_TOT (B_ * N_)     // 12608

// fused LDS map (shorts): 3 staging buffers (A 13312 + B 12288 each) = 76800
// shorts = 153.6 KB. Q/K/VT (end 40960) overlays A0/A1/A2+B0-head after loop.
#define ST_A0   0
#define ST_A1   13312
#define ST_A2   26624
#define ST_B0   39936
#define ST_B1   52224
#define ST_B2   64512
#define OFF_Q   0            // 208 rows x 64, XOR-swizzled slots
#define OFF_K   13312        // 208 rows x 64
#define OFF_VT  26624        // 64 rows (d) x 224 (tok), group-swizzled
#define LDS_TOT 76800

typedef __attribute__((ext_vector_type(8))) short bf8;
typedef __attribute__((ext_vector_type(4))) float f4;
typedef __attribute__((ext_vector_type(4))) unsigned short us4;

__device__ __forceinline__ unsigned short f2bf(float f) {
    unsigned u = __float_as_uint(f);
    u = (u + 0x7fffu + ((u >> 16) & 1u)) >> 16;
    return (unsigned short)u;
}

__device__ __forceinline__ void gl2lds16(const unsigned short* g, unsigned short* l) {
    __builtin_amdgcn_global_load_lds(
        (const __attribute__((address_space(1))) void*)g,
        (__attribute__((address_space(3))) void*)l, 16, 0, 0);
}

// Q/K LDS address (shorts): row-stride 64, 16B slot XOR-swizzled by row.
__device__ __forceinline__ int qkaddr(int row, int col) {
    return row * 64 + ((((col >> 3) ^ row) & 7) << 3) + (col & 7);
}
// VT LDS address (shorts): d-stride 224; 28 slots/row; XOR within slot groups
// (full 8-groups for s<24, the tail group of 4 uses a 2-bit XOR).
__device__ __forceinline__ int vtaddr(int d, int k) {
    int s = k >> 3;
    int s2 = (s < 24) ? ((s & 24) | ((s ^ d) & 7)) : (24 + ((s ^ d) & 3));
    return d * 224 + (s2 << 3) + (k & 7);
}

// ---------------- prep: fp32->bf16 converts (vectorized), bias gather ----------------
__global__ void k_prep(const float* __restrict__ x, const float* __restrict__ qkvw,
                       const float* __restrict__ projw, const float* __restrict__ rpb,
                       const int* __restrict__ relidx,
                       unsigned short* __restrict__ x_bf, unsigned short* __restrict__ qkvw_bf,
                       unsigned short* __restrict__ projw_bf, float* __restrict__ bias_hqk) {
    const int T = gridDim.x * blockDim.x;
    const int tid = blockIdx.x * blockDim.x + threadIdx.x;
    // all three bulk arrays have elem counts divisible by 4
    for (int i = tid; i < M_TOT * DIM_ / 4; i += T) {
        float4 v = ((const float4*)x)[i];
        us4 o = {f2bf(v.x), f2bf(v.y), f2bf(v.z), f2bf(v.w)};
        ((us4*)x_bf)[i] = o;
    }
    for (int i = tid; i < 3 * DIM_ * DIM_ / 4; i += T) {
        float4 v = ((const float4*)qkvw)[i];
        us4 o = {f2bf(v.x), f2bf(v.y), f2bf(v.z), f2bf(v.w)};
        ((us4*)qkvw_bf)[i] = o;
    }
    for (int i = tid; i < DIM_ * DIM_ / 4; i += T) {
        float4 v = ((const float4*)projw)[i];
        us4 o = {f2bf(v.x), f2bf(v.y), f2bf(v.z), f2bf(v.w)};
        ((us4*)projw_bf)[i] = o;
    }
    for (int i = tid; i < H_ * N_ * N_; i += T) {
        int h = i / (N_ * N_), qk = i - h * (N_ * N_);
        bias_hqk[i] = rpb[relidx[qk] * H_ + h];
    }
}

// ---------------- fused QKV + attention, one block (1024 thr) per (b,h) ----------------
__global__ __launch_bounds__(1024) void k_fused(const unsigned short* __restrict__ X,
                                                const unsigned short* __restrict__ Wqkv,
                                                const float* __restrict__ qb,
                                                const float* __restrict__ vbias,
                                                const float* __restrict__ bias_hqk,
                                                unsigned short* __restrict__ att_ws) {
    __shared__ unsigned short lds[LDS_TOT];

    const int t = threadIdx.x;                 // 0..1023
    const int w = t >> 6, lane = t & 63, ln = lane & 15, quad = lane >> 4;
    const int wm = w >> 2, wn = w & 3;         // SIMD-balanced: SIMD w%4 hosts wm 0..3
    const int srl = lane >> 3;                 // local row 0..7 within 8-row group
    const int src8 = (lane & 7) ^ srl;         // stored-slot -> fetched-chunk XOR swizzle

    // XCD swizzle: gid%8 -> XCD; contiguous 8-b group per XCD keeps x in its L2
    const int gid = blockIdx.x;                // 0..767
    const int local = gid >> 3;                // 0..95
    const int b = (gid & 7) * 8 + (local & 7);
    const int h = local >> 3;                  // 0..11

    const unsigned short* xb = X + (size_t)b * 197 * 768;

    // ---- staging (BK=64): 50 DMA instrs/phase (26 A row-groups + 24 B), 16 waves
    // reversed index: the 4-load waves (14,15) carry the lightest MFMA load (wm=3)
    auto stage = [&](int kt, int aOfs, int bOfs) {
#pragma unroll
        for (int i = 0; i < 4; ++i) {
            int idx = (15 - w) + 16 * i;
            if (idx >= 50) break;              // wave-uniform
            if (idx < 26) {                    // A: token rows idx*8..+7
                int tok = 8 * idx + srl;
                if (tok > 196) tok = 196;      // clamp; pad rows discarded later
                gl2lds16(xb + (size_t)tok * 768 + kt * 64 + src8 * 8,
                         &lds[aOfs + idx * 512]);
            } else {                           // B: weight rows (3 passes x 64)
                int bb = idx - 26;
                int rr = 8 * bb + srl;         // 0..191
                gl2lds16(Wqkv + (size_t)((rr >> 6) * 768 + h * 64 + (rr & 63)) * 768
                              + kt * 64 + src8 * 8,
                         &lds[bOfs + bb * 512]);
            }
        }
    };

    f4 acc[4][3] = {};                         // [mi][tl]: wave tile = (4m x 4n), 12 tiles

    auto compute = [&](int aOfs, int bOfs) {
#pragma unroll
        for (int ks = 0; ks < 2; ++ks) {
            bf8 bfr[3];
#pragma unroll
            for (int tl = 0; tl < 3; ++tl) {
                int rr = (wn * 3 + tl) * 16 + ln;
                int slot = (ks * 4 + quad) ^ (rr & 7);
                bfr[tl] = *(const bf8*)&lds[bOfs + rr * 64 + slot * 8];
            }
            __builtin_amdgcn_s_setprio(1);
#pragma unroll
            for (int mi = 0; mi < 4; ++mi) {
                int mt = wm + 4 * mi;
                if (mt >= 13) continue;        // wave-uniform (only wm>0, mi=3)
                int row = mt * 16 + ln;
                int slot = (ks * 4 + quad) ^ (row & 7);
                bf8 af = *(const bf8*)&lds[aOfs + row * 64 + slot * 8];
#pragma unroll
                for (int tl = 0; tl < 3; ++tl)
                    acc[mi][tl] = __builtin_amdgcn_mfma_f32_16x16x32_bf16(
                        af, bfr[tl], acc[mi][tl], 0, 0, 0);
            }
            __builtin_amdgcn_s_setprio(0);
        }
    };

    // ---- T3+T4 pipelined K-loop: depth-2 prefetch, 1 raw barrier/phase,
    //      counted vmcnt (FIFO completion per m135 makes vmcnt(3) drain
    //      exactly this wave's phase-kt loads while kt+1's stay in flight).
    const int stA[3] = {ST_A0, ST_A1, ST_A2};
    const int stB[3] = {ST_B0, ST_B1, ST_B2};
    stage(0, ST_A0, ST_B0);
    stage(1, ST_A1, ST_B1);
#pragma unroll
    for (int kt = 0; kt < 12; ++kt) {
        if (kt < 11) { __asm__ __volatile__("s_waitcnt vmcnt(3)" ::: "memory"); }
        else         { __asm__ __volatile__("s_waitcnt vmcnt(0)" ::: "memory"); }
        __builtin_amdgcn_sched_barrier(0);
        __builtin_amdgcn_s_barrier();          // buf kt DMA-complete on all waves;
        __builtin_amdgcn_sched_barrier(0);     // buf (kt-1) readers all finished
        if (kt + 2 < 12) stage(kt + 2, stA[(kt + 2) % 3], stB[(kt + 2) % 3]);
        compute(stA[kt % 3], stB[kt % 3]);
    }
    __syncthreads();                           // staging dead: epilogue overlays it

    // ---- epilogue: C/D layout row=quad*4+r, col=ln (m89-verified) -> LDS Q/K/VT
#pragma unroll
    for (int tl = 0; tl < 3; ++tl) {
        int tn = wn * 3 + tl;
        int p = tn >> 2;                       // 0=Q 1=K 2=V
        int col = (tn & 3) * 16 + ln;          // 0..63 within the pass
        int d = h * 64 + col;
        float bj = (p == 0) ? qb[d] : (p == 2) ? vbias[d] : 0.0f;
#pragma unroll
        for (int mi = 0; mi < 4; ++mi) {
            int mt = wm + 4 * mi;
            if (mt >= 13) continue;
#pragma unroll
            for (int r = 0; r < 4; ++r) {
                int row = mt * 16 + quad * 4 + r;  // 0..207 (pad rows masked later)
                float v = acc[mi][tl][r];
                if (p == 0)      lds[OFF_Q + qkaddr(row, col)] = f2bf((v + bj) * 0.125f);
                else if (p == 1) lds[OFF_K + qkaddr(row, col)] = f2bf(v);
                else             lds[OFF_VT + vtaddr(col, row)] = f2bf(v + bj);
            }
        }
    }
    // zero VT K-pad cols 208..223 (cols 197..207 hold finite clamped data)
    for (int idx = t; idx < 64 * 16; idx += 1024) {
        int d = idx >> 4, k = 208 + (idx & 15);
        lds[OFF_VT + vtaddr(d, k)] = 0;
    }
    __syncthreads();

    // ---- attention (Q/K/VT in LDS, P fully in-register), 16 waves, 13 m-tiles ----
    const float* bp = bias_hqk + (size_t)h * 197 * 197;

    for (int mt = w; mt < 13; mt += 16) {
        // Q as B-operand (hoisted): lane ln supplies q-row mt*16+ln
        bf8 qa[2];
#pragma unroll
        for (int ks = 0; ks < 2; ++ks)
            qa[ks] = *(const bf8*)&lds[OFF_Q + qkaddr(mt * 16 + ln, ks * 32 + quad * 8)];

        // swapped QK: S^T[k][q];  lane(ln,quad) reg r holds S[q=mt*16+ln][k=nt*16+quad*4+r]
        f4 sacc[13];
#pragma unroll
        for (int nt = 0; nt < 13; ++nt) sacc[nt] = (f4){0.f, 0.f, 0.f, 0.f};
        __builtin_amdgcn_s_setprio(1);
#pragma unroll
        for (int nt = 0; nt < 13; ++nt) {
#pragma unroll
            for (int ks = 0; ks < 2; ++ks) {
                bf8 ka = *(const bf8*)&lds[OFF_K + qkaddr(nt * 16 + ln, ks * 32 + quad * 8)];
                sacc[nt] = __builtin_amdgcn_mfma_f32_16x16x32_bf16(ka, qa[ks], sacc[nt], 0, 0, 0);
            }
        }
        __builtin_amdgcn_s_setprio(0);

        // softmax: row is lane-local across (nt,r); cross-lane only over quad (2 shfl)
        int qg = mt * 16 + ln;
        const float* brow = bp + (size_t)(qg < 197 ? qg : 196) * 197;
        float mx = -3.0e38f;
#pragma unroll
        for (int nt = 0; nt < 13; ++nt)
#pragma unroll
            for (int r = 0; r < 4; ++r) {
                int kg = nt * 16 + quad * 4 + r;
                float s = (kg < 197) ? (sacc[nt][r] + brow[kg]) : -3.0e38f;
                sacc[nt][r] = s;
                mx = fmaxf(mx, s);
            }
        mx = fmaxf(mx, __shfl_xor(mx, 16, 64));
        mx = fmaxf(mx, __shfl_xor(mx, 32, 64));
        float sum = 0.f;
#pragma unroll
        for (int nt = 0; nt < 13; ++nt)
#pragma unroll
            for (int r = 0; r < 4; ++r) {
                float pv = __expf(sacc[nt][r] - mx);
                sacc[nt][r] = pv;
                sum += pv;
            }
        sum += __shfl_xor(sum, 16, 64);
        sum += __shfl_xor(sum, 32, 64);
        float inv = 1.0f / sum;

        // pack normalized P to bf16 pairs: pk[nt][0]=(r0,r1), pk[nt][1]=(r2,r3)
        unsigned pk[14][2];
#pragma unroll
        for (int nt = 0; nt < 13; ++nt) {
            pk[nt][0] = (unsigned)f2bf(sacc[nt][0] * inv) |
                        ((unsigned)f2bf(sacc[nt][1] * inv) << 16);
            pk[nt][1] = (unsigned)f2bf(sacc[nt][2] * inv) |
                        ((unsigned)f2bf(sacc[nt][3] * inv) << 16);
        }
        pk[13][0] = 0; pk[13][1] = 0;          // K-pad 208..223 -> P = 0

        // PV: A-frag (lane ln = q-row ln, k-chunk = quad*8) built by ds_bpermute:
        // target quad q_t takes k=32ks+8q_t+[0..7] from source lanes
        // (ln + 32*(q_t&1)) and (+16), register set nt = 2ks + (q_t>>1).
        const int sA = (((lane & 15) | ((lane & 16) << 1)) << 2);
        const int sB = sA + 64;
        const bool hi = (lane & 32) != 0;
        f4 o[4];
#pragma unroll
        for (int j = 0; j < 4; ++j) o[j] = (f4){0.f, 0.f, 0.f, 0.f};
#pragma unroll
        for (int ks = 0; ks < 7; ++ks) {
            int b0 = __builtin_amdgcn_ds_bpermute(sA, (int)pk[2 * ks][0]);
            int b1 = __builtin_amdgcn_ds_bpermute(sA, (int)pk[2 * ks][1]);
            int b2 = __builtin_amdgcn_ds_bpermute(sB, (int)pk[2 * ks][0]);
            int b3 = __builtin_amdgcn_ds_bpermute(sB, (int)pk[2 * ks][1]);
            int c0 = __builtin_amdgcn_ds_bpermute(sA, (int)pk[2 * ks + 1][0]);
            int c1 = __builtin_amdgcn_ds_bpermute(sA, (int)pk[2 * ks + 1][1]);
            int c2 = __builtin_amdgcn_ds_bpermute(sB, (int)pk[2 * ks + 1][0]);
            int c3 = __builtin_amdgcn_ds_bpermute(sB, (int)pk[2 * ks + 1][1]);
            union { int u[4]; bf8 v; } uu;
            uu.u[0] = hi ? c0 : b0;
            uu.u[1] = hi ? c1 : b1;
            uu.u[2] = hi ? c2 : b2;
            uu.u[3] = hi ? c3 : b3;
            __builtin_amdgcn_s_setprio(1);
#pragma unroll
            for (int j = 0; j < 4; ++j) {
                bf8 vf = *(const bf8*)&lds[OFF_VT + vtaddr(j * 16 + ln, ks * 32 + quad * 8)];
                o[j] = __builtin_amdgcn_mfma_f32_16x16x32_bf16(uu.v, vf, o[j], 0, 0, 0);
            }
            __builtin_amdgcn_s_setprio(0);
        }
#pragma unroll
        for (int j = 0; j < 4; ++j)
#pragma unroll
            for (int r = 0; r < 4; ++r) {
                int tok = mt * 16 + quad * 4 + r;
                if (tok < 197)
                    att_ws[((size_t)b * 197 + tok) * 768 + h * 64 + j * 16 + ln] = f2bf(o[j][r]);
            }
    }
}

// ---------------- proj GEMM: (12608x768) @ (768x768)^T + bias -> fp32 out ----------------
// BK=32, superrow-packed LDS, triple-buffered, counted vmcnt(4).
// Per buffer (shorts): A 4096 (64 superrows x 64), B 4096. 3 buffers = 24576
// shorts = 48 KB -> 3 blocks/CU (3 waves/SIMD); all 594 blocks co-resident.
#define PJ_BUF 8192

__device__ __forceinline__ void pj_stage(const unsigned short* __restrict__ A,
                                         const unsigned short* __restrict__ Bm,
                                         int bm, int bn, int kt, int w, int srl, int src8,
                                         unsigned short* buf) {
    // superrow sr holds rows {2sr, 2sr+1}, 32 shorts each; chunk c of sr =
    // row 2sr+(c>>2), k-offset (c&3)*8. Stored slot (lane&7) gets fetched
    // chunk src8 = (lane&7)^srl  (involution with the compute-side read).
#pragma unroll
    for (int i = 0; i < 2; ++i) {
        int idx = w * 2 + i;                   // 0..7: superrow group idx*8+srl
        int gr = bm * 128 + 2 * (idx * 8 + srl) + (src8 >> 2);
        if (gr > M_TOT - 1) gr = M_TOT - 1;
        gl2lds16(A + (size_t)gr * 768 + kt * 32 + (src8 & 3) * 8,
                 &buf[idx * 512]);
        int gc = bn * 128 + 2 * (idx * 8 + srl) + (src8 >> 2);   // < 768
        gl2lds16(Bm + (size_t)gc * 768 + kt * 32 + (src8 & 3) * 8,
                 &buf[4096 + idx * 512]);
    }
}

__device__ __forceinline__ void pj_compute(const unsigned short* buf,
                                           int wm, int wn, int ln, int quad, f4 (*acc)[4]) {
    bf8 af[4], bfr[4];
#pragma unroll
    for (int i = 0; i < 4; ++i) {
        int row = wm * 64 + i * 16 + ln;
        int sr = row >> 1;
        int slot = (((row & 1) << 2) | quad) ^ (sr & 7);
        af[i] = *(const bf8*)&buf[sr * 64 + slot * 8];
    }
#pragma unroll
    for (int j = 0; j < 4; ++j) {
        int row = wn * 64 + j * 16 + ln;
        int sr = row >> 1;
        int slot = (((row & 1) << 2) | quad) ^ (sr & 7);
        bfr[j] = *(const bf8*)&buf[4096 + sr * 64 + slot * 8];
    }
    __builtin_amdgcn_s_setprio(1);
#pragma unroll
    for (int i = 0; i < 4; ++i)
#pragma unroll
        for (int j = 0; j < 4; ++j)
            acc[i][j] = __builtin_amdgcn_mfma_f32_16x16x32_bf16(af[i], bfr[j], acc[i][j], 0, 0, 0);
    __builtin_amdgcn_s_setprio(0);
}

__global__ __launch_bounds__(256, 3) void k_proj(const unsigned short* __restrict__ A,
                                                 const unsigned short* __restrict__ Bm,
                                                 const float* __restrict__ pb,
                                                 float* __restrict__ out) {
    __shared__ unsigned short plds[3 * PJ_BUF];
    const int t = threadIdx.x;
    const int w = t >> 6, lane = t & 63, ln = lane & 15, quad = lane >> 4;
    const int wm = w & 1, wn = w >> 1;

    const int gid = blockIdx.x;                 // panels: 8 bm x 6 bn = 48
    const int panel = gid / 48, rem = gid - panel * 48;
    const int pm0 = panel * 8;
    const int psz = (99 - pm0 < 8) ? (99 - pm0) : 8;
    const int bm = pm0 + rem % psz;
    const int bn = rem / psz;

    const int srl = lane >> 3;
    const int src8 = (lane & 7) ^ srl;

    f4 acc[4][4] = {};

    // T3+T4: depth-2 prefetch, 1 raw barrier/phase, counted vmcnt(4)
    // (4 DMA/wave/phase; at the wait, 8 outstanding -> leave kt+1's 4 in flight).
    pj_stage(A, Bm, bm, bn, 0, w, srl, src8, &plds[0]);
    pj_stage(A, Bm, bm, bn, 1, w, srl, src8, &plds[PJ_BUF]);
#pragma unroll
    for (int kt = 0; kt < 24; ++kt) {
        if (kt < 23) { __asm__ __volatile__("s_waitcnt vmcnt(4)" ::: "memory"); }
        else         { __asm__ __volatile__("s_waitcnt vmcnt(0)" ::: "memory"); }
        __builtin_amdgcn_sched_barrier(0);
        __builtin_amdgcn_s_barrier();          // buf kt DMA-complete on all waves;
        __builtin_amdgcn_sched_barrier(0);     // buf (kt-1) readers all finished
        if (kt + 2 < 24) pj_stage(A, Bm, bm, bn, kt + 2, w, srl, src8,
                                  &plds[((kt + 2) % 3) * PJ_BUF]);
        pj_compute(&plds[(kt % 3) * PJ_BUF], wm, wn, ln, quad, acc);
    }

#pragma unroll
    for (int i = 0; i < 4; ++i) {
#pragma unroll
        for (int r = 0; r < 4; ++r) {
            int row_g = bm * 128 + wm * 64 + i * 16 + quad * 4 + r;
            if (row_g >= M_TOT) continue;
#pragma unroll
            for (int j = 0; j < 4; ++j) {
                int col_g = bn * 128 + wn * 64 + j * 16 + ln;
                out[(size_t)row_g * 768 + col_g] = acc[i][j][r] + pb[col_g];
            }
        }
    }
}

extern "C" void kernel_launch(void* const* d_in, const int* in_sizes, int n_in,
                              void* d_out, int out_size, void* d_ws, size_t ws_size,
                              hipStream_t stream) {
    const float* x     = (const float*)d_in[0];
    const float* qkvw  = (const float*)d_in[1];
    const float* qb    = (const float*)d_in[2];
    const float* vb    = (const float*)d_in[3];
    const float* rpb   = (const float*)d_in[4];
    const float* projw = (const float*)d_in[5];
    const float* pb    = (const float*)d_in[6];
    const int*   ridx  = (const int*)d_in[7];
    float* out = (float*)d_out;

    char* ws = (char*)d_ws;
    size_t off = 0;
    auto alloc = [&](size_t bytes) -> void* {
        void* p = ws + off;
        off = (off + bytes + 255) & ~(size_t)255;
        return p;
    };
    unsigned short* x_bf     = (unsigned short*)alloc((size_t)M_TOT * DIM_ * 2);
    unsigned short* qkvw_bf  = (unsigned short*)alloc((size_t)3 * DIM_ * DIM_ * 2);
    unsigned short* projw_bf = (unsigned short*)alloc((size_t)DIM_ * DIM_ * 2);
    float*          bias_h   = (float*)alloc((size_t)H_ * N_ * N_ * 4);
    unsigned short* att_ws   = (unsigned short*)alloc((size_t)(M_TOT + 64) * DIM_ * 2);
    (void)ws_size; (void)in_sizes; (void)n_in; (void)out_size;

    k_prep<<<1200, 256, 0, stream>>>(x, qkvw, projw, rpb, ridx,
                                     x_bf, qkvw_bf, projw_bf, bias_h);
    k_fused<<<768, 1024, 0, stream>>>(x_bf, qkvw_bf, qb, vb, bias_h, att_ws);
    k_proj<<<594, 256, 0, stream>>>(att_ws, projw_bf, pb, out);
}

// Round 8
// 200.976 us; speedup vs baseline: 1.4918x; 1.0196x over previous
//
#include <hip/hip_runtime.h>

// AttentionWindow (BEiT windowed attention), MI355X gfx950.
// B=64 N=197 DIM=768 H=12 hd=64. bf16 MFMA (16x16x32), fp32 softmax.
// R15: on R14 (verified 204.9us). k_fused is LDS-BW bound (model: 224
//      ds_read_b128/phase ~= 2-2.7k cyc vs 375 cyc MFMA -> 27% MfmaUtil
//      ceiling matches measurement); fat-tile fixes are reg-walled at 1024
//      thr. This round cuts softmax-path traffic instead:
//      - bias table bf16, [12][197][208] padded rows: one aligned us4 load
//        per (nt,lane) instead of 4 scattered fp32 scalars (52->13 loads).
//      - bias folded into QK MFMA C-init (exact; kills 52 serial VALU adds
//        and hides gather latency under the MFMA loop).
//      Everything else byte-identical to R14.

#define B_    64
#define N_    197
#define DIM_  768
#define H_    12
#define HD_   64
#define M_TOT (B_ * N_)     // 12608

// fused LDS map (shorts): 3 staging buffers (A 13312 + B 12288 each) = 76800
// shorts = 153.6 KB. Q/K/VT (end 40960) overlays A0/A1/A2+B0-head after loop.
#define ST_A0   0
#define ST_A1   13312
#define ST_A2   26624
#define ST_B0   39936
#define ST_B1   52224
#define ST_B2   64512
#define OFF_Q   0            // 208 rows x 64, XOR-swizzled slots
#define OFF_K   13312        // 208 rows x 64
#define OFF_VT  26624        // 64 rows (d) x 224 (tok), group-swizzled
#define LDS_TOT 76800

typedef __attribute__((ext_vector_type(8))) short bf8;
typedef __attribute__((ext_vector_type(4))) float f4;
typedef __attribute__((ext_vector_type(4))) unsigned short us4;

__device__ __forceinline__ unsigned short f2bf(float f) {
    unsigned u = __float_as_uint(f);
    u = (u + 0x7fffu + ((u >> 16) & 1u)) >> 16;
    return (unsigned short)u;
}
__device__ __forceinline__ float bf2f(unsigned short u) {
    return __uint_as_float((unsigned)u << 16);
}

__device__ __forceinline__ void gl2lds16(const unsigned short* g, unsigned short* l) {
    __builtin_amdgcn_global_load_lds(
        (const __attribute__((address_space(1))) void*)g,
        (__attribute__((address_space(3))) void*)l, 16, 0, 0);
}

// Q/K LDS address (shorts): row-stride 64, 16B slot XOR-swizzled by row.
__device__ __forceinline__ int qkaddr(int row, int col) {
    return row * 64 + ((((col >> 3) ^ row) & 7) << 3) + (col & 7);
}
// VT LDS address (shorts): d-stride 224; 28 slots/row; XOR within slot groups
// (full 8-groups for s<24, the tail group of 4 uses a 2-bit XOR).
__device__ __forceinline__ int vtaddr(int d, int k) {
    int s = k >> 3;
    int s2 = (s < 24) ? ((s & 24) | ((s ^ d) & 7)) : (24 + ((s ^ d) & 3));
    return d * 224 + (s2 << 3) + (k & 7);
}

// ---------------- prep: fp32->bf16 converts (vectorized), bias gather ----------------
__global__ void k_prep(const float* __restrict__ x, const float* __restrict__ qkvw,
                       const float* __restrict__ projw, const float* __restrict__ rpb,
                       const int* __restrict__ relidx,
                       unsigned short* __restrict__ x_bf, unsigned short* __restrict__ qkvw_bf,
                       unsigned short* __restrict__ projw_bf,
                       unsigned short* __restrict__ bias_bf) {
    const int T = gridDim.x * blockDim.x;
    const int tid = blockIdx.x * blockDim.x + threadIdx.x;
    // all three bulk arrays have elem counts divisible by 4
    for (int i = tid; i < M_TOT * DIM_ / 4; i += T) {
        float4 v = ((const float4*)x)[i];
        us4 o = {f2bf(v.x), f2bf(v.y), f2bf(v.z), f2bf(v.w)};
        ((us4*)x_bf)[i] = o;
    }
    for (int i = tid; i < 3 * DIM_ * DIM_ / 4; i += T) {
        float4 v = ((const float4*)qkvw)[i];
        us4 o = {f2bf(v.x), f2bf(v.y), f2bf(v.z), f2bf(v.w)};
        ((us4*)qkvw_bf)[i] = o;
    }
    for (int i = tid; i < DIM_ * DIM_ / 4; i += T) {
        float4 v = ((const float4*)projw)[i];
        us4 o = {f2bf(v.x), f2bf(v.y), f2bf(v.z), f2bf(v.w)};
        ((us4*)projw_bf)[i] = o;
    }
    // bias: bf16, padded layout [h][q][208]; cols 197..207 = 0
    for (int i = tid; i < H_ * N_ * 208; i += T) {
        int h = i / (N_ * 208);
        int rem = i - h * (N_ * 208);
        int q = rem / 208, k = rem - (rem / 208) * 208;
        bias_bf[i] = (k < N_) ? f2bf(rpb[relidx[q * N_ + k] * H_ + h])
                              : (unsigned short)0;
    }
}

// ---------------- fused QKV + attention, one block (1024 thr) per (b,h) ----------------
__global__ __launch_bounds__(1024) void k_fused(const unsigned short* __restrict__ X,
                                                const unsigned short* __restrict__ Wqkv,
                                                const float* __restrict__ qb,
                                                const float* __restrict__ vbias,
                                                const unsigned short* __restrict__ bias_bf,
                                                unsigned short* __restrict__ att_ws) {
    __shared__ unsigned short lds[LDS_TOT];

    const int t = threadIdx.x;                 // 0..1023
    const int w = t >> 6, lane = t & 63, ln = lane & 15, quad = lane >> 4;
    const int wm = w >> 2, wn = w & 3;         // SIMD-balanced: SIMD w%4 hosts wm 0..3
    const int srl = lane >> 3;                 // local row 0..7 within 8-row group
    const int src8 = (lane & 7) ^ srl;         // stored-slot -> fetched-chunk XOR swizzle

    // XCD swizzle: gid%8 -> XCD; contiguous 8-b group per XCD keeps x in its L2
    const int gid = blockIdx.x;                // 0..767
    const int local = gid >> 3;                // 0..95
    const int b = (gid & 7) * 8 + (local & 7);
    const int h = local >> 3;                  // 0..11

    const unsigned short* xb = X + (size_t)b * 197 * 768;

    // ---- staging (BK=64): 50 DMA instrs/phase (26 A row-groups + 24 B), 16 waves
    // reversed index: the 4-load waves (14,15) carry the lightest MFMA load (wm=3)
    auto stage = [&](int kt, int aOfs, int bOfs) {
#pragma unroll
        for (int i = 0; i < 4; ++i) {
            int idx = (15 - w) + 16 * i;
            if (idx >= 50) break;              // wave-uniform
            if (idx < 26) {                    // A: token rows idx*8..+7
                int tok = 8 * idx + srl;
                if (tok > 196) tok = 196;      // clamp; pad rows discarded later
                gl2lds16(xb + (size_t)tok * 768 + kt * 64 + src8 * 8,
                         &lds[aOfs + idx * 512]);
            } else {                           // B: weight rows (3 passes x 64)
                int bb = idx - 26;
                int rr = 8 * bb + srl;         // 0..191
                gl2lds16(Wqkv + (size_t)((rr >> 6) * 768 + h * 64 + (rr & 63)) * 768
                              + kt * 64 + src8 * 8,
                         &lds[bOfs + bb * 512]);
            }
        }
    };

    f4 acc[4][3] = {};                         // [mi][tl]: wave tile = (4m x 4n), 12 tiles

    auto compute = [&](int aOfs, int bOfs) {
#pragma unroll
        for (int ks = 0; ks < 2; ++ks) {
            bf8 bfr[3];
#pragma unroll
            for (int tl = 0; tl < 3; ++tl) {
                int rr = (wn * 3 + tl) * 16 + ln;
                int slot = (ks * 4 + quad) ^ (rr & 7);
                bfr[tl] = *(const bf8*)&lds[bOfs + rr * 64 + slot * 8];
            }
            __builtin_amdgcn_s_setprio(1);
#pragma unroll
            for (int mi = 0; mi < 4; ++mi) {
                int mt = wm + 4 * mi;
                if (mt >= 13) continue;        // wave-uniform (only wm>0, mi=3)
                int row = mt * 16 + ln;
                int slot = (ks * 4 + quad) ^ (row & 7);
                bf8 af = *(const bf8*)&lds[aOfs + row * 64 + slot * 8];
#pragma unroll
                for (int tl = 0; tl < 3; ++tl)
                    acc[mi][tl] = __builtin_amdgcn_mfma_f32_16x16x32_bf16(
                        af, bfr[tl], acc[mi][tl], 0, 0, 0);
            }
            __builtin_amdgcn_s_setprio(0);
        }
    };

    // ---- T3+T4 pipelined K-loop: depth-2 prefetch, 1 raw barrier/phase,
    //      counted vmcnt (FIFO completion per m135 makes vmcnt(3) drain
    //      exactly this wave's phase-kt loads while kt+1's stay in flight).
    const int stA[3] = {ST_A0, ST_A1, ST_A2};
    const int stB[3] = {ST_B0, ST_B1, ST_B2};
    stage(0, ST_A0, ST_B0);
    stage(1, ST_A1, ST_B1);
#pragma unroll
    for (int kt = 0; kt < 12; ++kt) {
        if (kt < 11) { __asm__ __volatile__("s_waitcnt vmcnt(3)" ::: "memory"); }
        else         { __asm__ __volatile__("s_waitcnt vmcnt(0)" ::: "memory"); }
        __builtin_amdgcn_sched_barrier(0);
        __builtin_amdgcn_s_barrier();          // buf kt DMA-complete on all waves;
        __builtin_amdgcn_sched_barrier(0);     // buf (kt-1) readers all finished
        if (kt + 2 < 12) stage(kt + 2, stA[(kt + 2) % 3], stB[(kt + 2) % 3]);
        compute(stA[kt % 3], stB[kt % 3]);
    }
    __syncthreads();                           // staging dead: epilogue overlays it

    // ---- epilogue: C/D layout row=quad*4+r, col=ln (m89-verified) -> LDS Q/K/VT
#pragma unroll
    for (int tl = 0; tl < 3; ++tl) {
        int tn = wn * 3 + tl;
        int p = tn >> 2;                       // 0=Q 1=K 2=V
        int col = (tn & 3) * 16 + ln;          // 0..63 within the pass
        int d = h * 64 + col;
        float bj = (p == 0) ? qb[d] : (p == 2) ? vbias[d] : 0.0f;
#pragma unroll
        for (int mi = 0; mi < 4; ++mi) {
            int mt = wm + 4 * mi;
            if (mt >= 13) continue;
#pragma unroll
            for (int r = 0; r < 4; ++r) {
                int row = mt * 16 + quad * 4 + r;  // 0..207 (pad rows masked later)
                float v = acc[mi][tl][r];
                if (p == 0)      lds[OFF_Q + qkaddr(row, col)] = f2bf((v + bj) * 0.125f);
                else if (p == 1) lds[OFF_K + qkaddr(row, col)] = f2bf(v);
                else             lds[OFF_VT + vtaddr(col, row)] = f2bf(v + bj);
            }
        }
    }
    // zero VT K-pad cols 208..223 (cols 197..207 hold finite clamped data)
    for (int idx = t; idx < 64 * 16; idx += 1024) {
        int d = idx >> 4, k = 208 + (idx & 15);
        lds[OFF_VT + vtaddr(d, k)] = 0;
    }
    __syncthreads();

    // ---- attention (Q/K/VT in LDS, P fully in-register), 16 waves, 13 m-tiles ----
    const unsigned short* bp = bias_bf + (size_t)h * 197 * 208;

    for (int mt = w; mt < 13; mt += 16) {
        // Q as B-operand (hoisted): lane ln supplies q-row mt*16+ln
        bf8 qa[2];
#pragma unroll
        for (int ks = 0; ks < 2; ++ks)
            qa[ks] = *(const bf8*)&lds[OFF_Q + qkaddr(mt * 16 + ln, ks * 32 + quad * 8)];

        // swapped QK: S^T[k][q]; lane(ln,quad) reg r holds S[q=mt*16+ln][k=nt*16+quad*4+r]
        // C-init = rel-pos bias fragment (exact: MFMA accumulates S on top).
        int qg = mt * 16 + ln;
        const unsigned short* brow = bp + (size_t)(qg < 197 ? qg : 196) * 208;
        f4 sacc[13];
#pragma unroll
        for (int nt = 0; nt < 13; ++nt) {
            us4 bq = *(const us4*)&brow[nt * 16 + quad * 4];
            sacc[nt] = (f4){bf2f(bq[0]), bf2f(bq[1]), bf2f(bq[2]), bf2f(bq[3])};
        }
        __builtin_amdgcn_s_setprio(1);
#pragma unroll
        for (int nt = 0; nt < 13; ++nt) {
#pragma unroll
            for (int ks = 0; ks < 2; ++ks) {
                bf8 ka = *(const bf8*)&lds[OFF_K + qkaddr(nt * 16 + ln, ks * 32 + quad * 8)];
                sacc[nt] = __builtin_amdgcn_mfma_f32_16x16x32_bf16(ka, qa[ks], sacc[nt], 0, 0, 0);
            }
        }
        __builtin_amdgcn_s_setprio(0);

        // softmax: row is lane-local across (nt,r); cross-lane only over quad (2 shfl)
        float mx = -3.0e38f;
#pragma unroll
        for (int nt = 0; nt < 13; ++nt)
#pragma unroll
            for (int r = 0; r < 4; ++r) {
                int kg = nt * 16 + quad * 4 + r;
                float s = (kg < 197) ? sacc[nt][r] : -3.0e38f;
                sacc[nt][r] = s;
                mx = fmaxf(mx, s);
            }
        mx = fmaxf(mx, __shfl_xor(mx, 16, 64));
        mx = fmaxf(mx, __shfl_xor(mx, 32, 64));
        float sum = 0.f;
#pragma unroll
        for (int nt = 0; nt < 13; ++nt)
#pragma unroll
            for (int r = 0; r < 4; ++r) {
                float pv = __expf(sacc[nt][r] - mx);
                sacc[nt][r] = pv;
                sum += pv;
            }
        sum += __shfl_xor(sum, 16, 64);
        sum += __shfl_xor(sum, 32, 64);
        float inv = 1.0f / sum;

        // pack normalized P to bf16 pairs: pk[nt][0]=(r0,r1), pk[nt][1]=(r2,r3)
        unsigned pk[14][2];
#pragma unroll
        for (int nt = 0; nt < 13; ++nt) {
            pk[nt][0] = (unsigned)f2bf(sacc[nt][0] * inv) |
                        ((unsigned)f2bf(sacc[nt][1] * inv) << 16);
            pk[nt][1] = (unsigned)f2bf(sacc[nt][2] * inv) |
                        ((unsigned)f2bf(sacc[nt][3] * inv) << 16);
        }
        pk[13][0] = 0; pk[13][1] = 0;          // K-pad 208..223 -> P = 0

        // PV: A-frag (lane ln = q-row ln, k-chunk = quad*8) built by ds_bpermute:
        // target quad q_t takes k=32ks+8q_t+[0..7] from source lanes
        // (ln + 32*(q_t&1)) and (+16), register set nt = 2ks + (q_t>>1).
        const int sA = (((lane & 15) | ((lane & 16) << 1)) << 2);
        const int sB = sA + 64;
        const bool hi = (lane & 32) != 0;
        f4 o[4];
#pragma unroll
        for (int j = 0; j < 4; ++j) o[j] = (f4){0.f, 0.f, 0.f, 0.f};
#pragma unroll
        for (int ks = 0; ks < 7; ++ks) {
            int b0 = __builtin_amdgcn_ds_bpermute(sA, (int)pk[2 * ks][0]);
            int b1 = __builtin_amdgcn_ds_bpermute(sA, (int)pk[2 * ks][1]);
            int b2 = __builtin_amdgcn_ds_bpermute(sB, (int)pk[2 * ks][0]);
            int b3 = __builtin_amdgcn_ds_bpermute(sB, (int)pk[2 * ks][1]);
            int c0 = __builtin_amdgcn_ds_bpermute(sA, (int)pk[2 * ks + 1][0]);
            int c1 = __builtin_amdgcn_ds_bpermute(sA, (int)pk[2 * ks + 1][1]);
            int c2 = __builtin_amdgcn_ds_bpermute(sB, (int)pk[2 * ks + 1][0]);
            int c3 = __builtin_amdgcn_ds_bpermute(sB, (int)pk[2 * ks + 1][1]);
            union { int u[4]; bf8 v; } uu;
            uu.u[0] = hi ? c0 : b0;
            uu.u[1] = hi ? c1 : b1;
            uu.u[2] = hi ? c2 : b2;
            uu.u[3] = hi ? c3 : b3;
            __builtin_amdgcn_s_setprio(1);
#pragma unroll
            for (int j = 0; j < 4; ++j) {
                bf8 vf = *(const bf8*)&lds[OFF_VT + vtaddr(j * 16 + ln, ks * 32 + quad * 8)];
                o[j] = __builtin_amdgcn_mfma_f32_16x16x32_bf16(uu.v, vf, o[j], 0, 0, 0);
            }
            __builtin_amdgcn_s_setprio(0);
        }
#pragma unroll
        for (int j = 0; j < 4; ++j)
#pragma unroll
            for (int r = 0; r < 4; ++r) {
                int tok = mt * 16 + quad * 4 + r;
                if (tok < 197)
                    att_ws[((size_t)b * 197 + tok) * 768 + h * 64 + j * 16 + ln] = f2bf(o[j][r]);
            }
    }
}

// ---------------- proj GEMM: (12608x768) @ (768x768)^T + bias -> fp32 out ----------------
// BK=32, superrow-packed LDS, triple-buffered, counted vmcnt(4).
// Per buffer (shorts): A 4096 (64 superrows x 64), B 4096. 3 buffers = 24576
// shorts = 48 KB -> 3 blocks/CU (3 waves/SIMD); all 594 blocks co-resident.
#define PJ_BUF 8192

__device__ __forceinline__ void pj_stage(const unsigned short* __restrict__ A,
                                         const unsigned short* __restrict__ Bm,
                                         int bm, int bn, int kt, int w, int srl, int src8,
                                         unsigned short* buf) {
    // superrow sr holds rows {2sr, 2sr+1}, 32 shorts each; chunk c of sr =
    // row 2sr+(c>>2), k-offset (c&3)*8. Stored slot (lane&7) gets fetched
    // chunk src8 = (lane&7)^srl  (involution with the compute-side read).
#pragma unroll
    for (int i = 0; i < 2; ++i) {
        int idx = w * 2 + i;                   // 0..7: superrow group idx*8+srl
        int gr = bm * 128 + 2 * (idx * 8 + srl) + (src8 >> 2);
        if (gr > M_TOT - 1) gr = M_TOT - 1;
        gl2lds16(A + (size_t)gr * 768 + kt * 32 + (src8 & 3) * 8,
                 &buf[idx * 512]);
        int gc = bn * 128 + 2 * (idx * 8 + srl) + (src8 >> 2);   // < 768
        gl2lds16(Bm + (size_t)gc * 768 + kt * 32 + (src8 & 3) * 8,
                 &buf[4096 + idx * 512]);
    }
}

__device__ __forceinline__ void pj_compute(const unsigned short* buf,
                                           int wm, int wn, int ln, int quad, f4 (*acc)[4]) {
    bf8 af[4], bfr[4];
#pragma unroll
    for (int i = 0; i < 4; ++i) {
        int row = wm * 64 + i * 16 + ln;
        int sr = row >> 1;
        int slot = (((row & 1) << 2) | quad) ^ (sr & 7);
        af[i] = *(const bf8*)&buf[sr * 64 + slot * 8];
    }
#pragma unroll
    for (int j = 0; j < 4; ++j) {
        int row = wn * 64 + j * 16 + ln;
        int sr = row >> 1;
        int slot = (((row & 1) << 2) | quad) ^ (sr & 7);
        bfr[j] = *(const bf8*)&buf[4096 + sr * 64 + slot * 8];
    }
    __builtin_amdgcn_s_setprio(1);
#pragma unroll
    for (int i = 0; i < 4; ++i)
#pragma unroll
        for (int j = 0; j < 4; ++j)
            acc[i][j] = __builtin_amdgcn_mfma_f32_16x16x32_bf16(af[i], bfr[j], acc[i][j], 0, 0, 0);
    __builtin_amdgcn_s_setprio(0);
}

__global__ __launch_bounds__(256, 3) void k_proj(const unsigned short* __restrict__ A,
                                                 const unsigned short* __restrict__ Bm,
                                                 const float* __restrict__ pb,
                                                 float* __restrict__ out) {
    __shared__ unsigned short plds[3 * PJ_BUF];
    const int t = threadIdx.x;
    const int w = t >> 6, lane = t & 63, ln = lane & 15, quad = lane >> 4;
    const int wm = w & 1, wn = w >> 1;

    const int gid = blockIdx.x;                 // panels: 8 bm x 6 bn = 48
    const int panel = gid / 48, rem = gid - panel * 48;
    const int pm0 = panel * 8;
    const int psz = (99 - pm0 < 8) ? (99 - pm0) : 8;
    const int bm = pm0 + rem % psz;
    const int bn = rem / psz;

    const int srl = lane >> 3;
    const int src8 = (lane & 7) ^ srl;

    f4 acc[4][4] = {};

    // T3+T4: depth-2 prefetch, 1 raw barrier/phase, counted vmcnt(4)
    // (4 DMA/wave/phase; at the wait, 8 outstanding -> leave kt+1's 4 in flight).
    pj_stage(A, Bm, bm, bn, 0, w, srl, src8, &plds[0]);
    pj_stage(A, Bm, bm, bn, 1, w, srl, src8, &plds[PJ_BUF]);
#pragma unroll
    for (int kt = 0; kt < 24; ++kt) {
        if (kt < 23) { __asm__ __volatile__("s_waitcnt vmcnt(4)" ::: "memory"); }
        else         { __asm__ __volatile__("s_waitcnt vmcnt(0)" ::: "memory"); }
        __builtin_amdgcn_sched_barrier(0);
        __builtin_amdgcn_s_barrier();          // buf kt DMA-complete on all waves;
        __builtin_amdgcn_sched_barrier(0);     // buf (kt-1) readers all finished
        if (kt + 2 < 24) pj_stage(A, Bm, bm, bn, kt + 2, w, srl, src8,
                                  &plds[((kt + 2) % 3) * PJ_BUF]);
        pj_compute(&plds[(kt % 3) * PJ_BUF], wm, wn, ln, quad, acc);
    }

#pragma unroll
    for (int i = 0; i < 4; ++i) {
#pragma unroll
        for (int r = 0; r < 4; ++r) {
            int row_g = bm * 128 + wm * 64 + i * 16 + quad * 4 + r;
            if (row_g >= M_TOT) continue;
#pragma unroll
            for (int j = 0; j < 4; ++j) {
                int col_g = bn * 128 + wn * 64 + j * 16 + ln;
                out[(size_t)row_g * 768 + col_g] = acc[i][j][r] + pb[col_g];
            }
        }
    }
}

extern "C" void kernel_launch(void* const* d_in, const int* in_sizes, int n_in,
                              void* d_out, int out_size, void* d_ws, size_t ws_size,
                              hipStream_t stream) {
    const float* x     = (const float*)d_in[0];
    const float* qkvw  = (const float*)d_in[1];
    const float* qb    = (const float*)d_in[2];
    const float* vb    = (const float*)d_in[3];
    const float* rpb   = (const float*)d_in[4];
    const float* projw = (const float*)d_in[5];
    const float* pb    = (const float*)d_in[6];
    const int*   ridx  = (const int*)d_in[7];
    float* out = (float*)d_out;

    char* ws = (char*)d_ws;
    size_t off = 0;
    auto alloc = [&](size_t bytes) -> void* {
        void* p = ws + off;
        off = (off + bytes + 255) & ~(size_t)255;
        return p;
    };
    unsigned short* x_bf     = (unsigned short*)alloc((size_t)M_TOT * DIM_ * 2);
    unsigned short* qkvw_bf  = (unsigned short*)alloc((size_t)3 * DIM_ * DIM_ * 2);
    unsigned short* projw_bf = (unsigned short*)alloc((size_t)DIM_ * DIM_ * 2);
    unsigned short* bias_bf  = (unsigned short*)alloc((size_t)H_ * N_ * 208 * 2);
    unsigned short* att_ws   = (unsigned short*)alloc((size_t)(M_TOT + 64) * DIM_ * 2);
    (void)ws_size; (void)in_sizes; (void)n_in; (void)out_size;

    k_prep<<<1200, 256, 0, stream>>>(x, qkvw, projw, rpb, ridx,
                                     x_bf, qkvw_bf, projw_bf, bias_bf);
    k_fused<<<768, 1024, 0, stream>>>(x_bf, qkvw_bf, qb, vb, bias_bf, att_ws);
    k_proj<<<594, 256, 0, stream>>>(att_ws, projw_bf, pb, out);
}